// Round 1
// baseline (256.886 us; speedup 1.0000x reference)
//
#include <hip/hip_runtime.h>

#define HH 256
#define WW 256
#define BB 4
#define HW (HH*WW)
#define N_ITER 20
#define EPSV 1e-8f

__device__ __forceinline__ float ldz(const float* __restrict__ p, int y, int x) {
    if ((unsigned)y < HH && (unsigned)x < WW) return p[y*WW + x];
    return 0.0f;
}

// cross-correlation with SX = [[-1,0,1],[-2,0,2],[-1,0,1]]
__device__ __forceinline__ float sobelX(const float* __restrict__ p, int y, int x) {
    return -ldz(p,y-1,x-1) + ldz(p,y-1,x+1)
         - 2.0f*ldz(p,y,x-1) + 2.0f*ldz(p,y,x+1)
         - ldz(p,y+1,x-1) + ldz(p,y+1,x+1);
}
// cross-correlation with SY = [[-1,-2,-1],[0,0,0],[1,2,1]]
__device__ __forceinline__ float sobelY(const float* __restrict__ p, int y, int x) {
    return -ldz(p,y-1,x-1) - 2.0f*ldz(p,y-1,x) - ldz(p,y-1,x+1)
          + ldz(p,y+1,x-1) + 2.0f*ldz(p,y+1,x) + ldz(p,y+1,x+1);
}

__global__ void tvl1_init(const float* __restrict__ xin, float* __restrict__ u,
                          float* __restrict__ p1, float* __restrict__ p2,
                          float* __restrict__ gx, float* __restrict__ gy,
                          float* __restrict__ rc) {
    int x = blockIdx.x*blockDim.x + threadIdx.x;
    int y = blockIdx.y*blockDim.y + threadIdx.y;
    int b = blockIdx.z;
    int idx = y*WW + x;
    int pb = b*2*HW;
    const float* im1 = xin + pb + HW;     // channel 1
    float i1 = im1[idx];
    rc[b*HW + idx] = i1 - xin[pb + idx];  // im1 - im0
    gx[b*HW + idx] = sobelX(im1, y, x);
    gy[b*HW + idx] = sobelY(im1, y, x);
    u[pb + idx] = 0.0f;  u[pb + HW + idx] = 0.0f;
    p1[pb + idx] = 0.0f; p1[pb + HW + idx] = 0.0f;
    p2[pb + idx] = 0.0f; p2[pb + HW + idx] = 0.0f;
}

__global__ void tvl1_u(float* __restrict__ u,
                       const float* __restrict__ p1, const float* __restrict__ p2,
                       const float* __restrict__ gx, const float* __restrict__ gy,
                       const float* __restrict__ rc,
                       const float* __restrict__ lam, const float* __restrict__ tau,
                       const float* __restrict__ the) {
    int x = blockIdx.x*blockDim.x + threadIdx.x;
    int y = blockIdx.y*blockDim.y + threadIdx.y;
    int b = blockIdx.z;
    int idx = y*WW + x;
    int pb = b*2*HW;
    const float theta = the[0];
    const float tl = theta * lam[0];

    float g_x = gx[b*HW + idx], g_y = gy[b*HW + idx];
    float ng  = g_x*g_x + g_y*g_y + EPSV;
    float u0  = u[pb + idx], u1 = u[pb + HW + idx];
    float rho = rc[b*HW + idx] + g_x*u0 + g_y*u1;
    float th  = tl * ng;
    float sgn = (rho > 0.0f) ? 1.0f : ((rho < 0.0f) ? -1.0f : 0.0f);
    float d   = (fabsf(rho) < th) ? (rho / ng) : (tl * sgn);
    float v0 = u0 - d*g_x;
    float v1 = u1 - d*g_y;

    const float* p1c0 = p1 + pb;       const float* p1c1 = p1 + pb + HW;
    const float* p2c0 = p2 + pb;       const float* p2c1 = p2 + pb + HW;
    float div0 = sobelX(p1c0, y, x) + sobelY(p2c0, y, x);
    float div1 = sobelX(p1c1, y, x) + sobelY(p2c1, y, x);

    u[pb + idx]      = v0 + theta*div0;
    u[pb + HW + idx] = v1 + theta*div1;
}

__global__ void tvl1_p(const float* __restrict__ u,
                       float* __restrict__ p1, float* __restrict__ p2,
                       const float* __restrict__ tau, const float* __restrict__ the) {
    int x = blockIdx.x*blockDim.x + threadIdx.x;
    int y = blockIdx.y*blockDim.y + threadIdx.y;
    int b = blockIdx.z;
    int idx = y*WW + x;
    int pb = b*2*HW;
    const float r = tau[0] / the[0];

    const float* u0 = u + pb;
    const float* u1 = u + pb + HW;
    float g1x = sobelX(u0, y, x), g1y = sobelY(u0, y, x);
    float g2x = sobelX(u1, y, x), g2y = sobelY(u1, y, x);
    float d1 = 1.0f + r*(fabsf(g1x) + fabsf(g1y));
    float d2 = 1.0f + r*(fabsf(g2x) + fabsf(g2y));
    float inv1 = 1.0f / d1, inv2 = 1.0f / d2;

    p1[pb + idx]      = (p1[pb + idx]      + r*g1x) * inv1;
    p1[pb + HW + idx] = (p1[pb + HW + idx] + r*g1y) * inv1;
    p2[pb + idx]      = (p2[pb + idx]      + r*g2x) * inv2;
    p2[pb + HW + idx] = (p2[pb + HW + idx] + r*g2y) * inv2;
}

extern "C" void kernel_launch(void* const* d_in, const int* in_sizes, int n_in,
                              void* d_out, int out_size, void* d_ws, size_t ws_size,
                              hipStream_t stream) {
    const float* xin = (const float*)d_in[0];
    const float* lam = (const float*)d_in[1];
    const float* tau = (const float*)d_in[2];
    const float* the = (const float*)d_in[3];
    float* u = (float*)d_out;              // u lives in d_out (B,2,H,W)

    float* ws = (float*)d_ws;
    float* p1 = ws;                        // B*2*HW
    float* p2 = ws + (size_t)BB*2*HW;      // B*2*HW
    float* gx = ws + (size_t)2*BB*2*HW;    // B*HW
    float* gy = gx + (size_t)BB*HW;        // B*HW
    float* rc = gy + (size_t)BB*HW;        // B*HW

    dim3 blk(64, 4, 1);
    dim3 grd(WW/64, HH/4, BB);

    tvl1_init<<<grd, blk, 0, stream>>>(xin, u, p1, p2, gx, gy, rc);
    for (int i = 0; i < N_ITER; ++i) {
        tvl1_u<<<grd, blk, 0, stream>>>(u, p1, p2, gx, gy, rc, lam, tau, the);
        if (i < N_ITER - 1)  // last p-update never feeds the output
            tvl1_p<<<grd, blk, 0, stream>>>(u, p1, p2, tau, the);
    }
}